// Round 4
// baseline (511.625 us; speedup 1.0000x reference)
//
#include <hip/hip_runtime.h>
#include <hip/hip_bf16.h>
#include <math.h>

// Problem constants: B=4, D=1024, N=2048, K=1024, fp32 in/out.
#define BB 4
#define DD 1024
#define NN 2048
#define KK 1024
#define NT128 16            // NN/128
#define NTRI 136            // 16*17/2 lower-triangular 128x128 tiles
#define TRI_ELEMS 16384     // 128*128

typedef __attribute__((ext_vector_type(4))) float f32x4;
typedef __attribute__((ext_vector_type(8))) short bfrag;

typedef __attribute__((address_space(1))) const unsigned int gu32;
typedef __attribute__((address_space(3))) unsigned int lu32;

// async global->LDS, 16B per lane; LDS dest = base + lane*16 (wave-uniform base)
__device__ __forceinline__ void async16(const void* g, void* l) {
  __builtin_amdgcn_global_load_lds((gu32*)g, (lu32*)l, 16, 0, 0);
}

__device__ __forceinline__ ushort f2b(float f) {  // fp32 -> bf16 RNE
  union { float f; unsigned u; } c; c.f = f;
  unsigned u = c.u + 0x7fffu + ((c.u >> 16) & 1u);
  return (ushort)(u >> 16);
}
__device__ __forceinline__ float b2f(ushort h) {
  union { unsigned u; float f; } c; c.u = ((unsigned)h) << 16;
  return c.f;
}

// ---------------------------------------------------------------------------
// x [b][d][n] fp32 -> x_hi (bf16, same layout), xT_hi/xT_lo (bf16, [b][n][d])
// ---------------------------------------------------------------------------
__global__ __launch_bounds__(256) void transpose_split(
    const float* __restrict__ x, ushort* __restrict__ xhi,
    ushort* __restrict__ xTh, ushort* __restrict__ xTl) {
  const int b = blockIdx.z;
  const int n0 = blockIdx.x * 32, d0 = blockIdx.y * 32;
  const int tx = threadIdx.x, ty = threadIdx.y;
  __shared__ float tile[32][33];
  const float* xb = x + (long)b * DD * NN;
  ushort* xhb = xhi + (long)b * DD * NN;
#pragma unroll
  for (int r = 0; r < 4; ++r) {
    const int dl = ty + r * 8;
    const float v = xb[(long)(d0 + dl) * NN + n0 + tx];
    tile[dl][tx] = v;
    xhb[(long)(d0 + dl) * NN + n0 + tx] = f2b(v);
  }
  __syncthreads();
#pragma unroll
  for (int r = 0; r < 4; ++r) {
    const int nl = ty + r * 8;
    const float v = tile[tx][nl];
    const ushort h = f2b(v);
    const long o = (long)b * NN * DD + (long)(n0 + nl) * DD + d0 + tx;
    xTh[o] = h;
    xTl[o] = f2b(v - b2f(h));
  }
}

// ---------------------------------------------------------------------------
// All four weight transposes in ONE dispatch. z selects W; z<2 also writes lo.
// W (K x D fp32, row-major [k][d]) -> WT [d][k] bf16.
// ---------------------------------------------------------------------------
__global__ __launch_bounds__(256) void wtrans4(
    const float* __restrict__ WQ, const float* __restrict__ WK,
    const float* __restrict__ WV, const float* __restrict__ WO,
    ushort* __restrict__ qh, ushort* __restrict__ ql,
    ushort* __restrict__ kh, ushort* __restrict__ kl_,
    ushort* __restrict__ vh, ushort* __restrict__ oh) {
  const int z = blockIdx.z;
  const float* W = (z == 0) ? WQ : (z == 1) ? WK : (z == 2) ? WV : WO;
  ushort* Th = (z == 0) ? qh : (z == 1) ? kh : (z == 2) ? vh : oh;
  ushort* Tl = (z == 0) ? ql : (z == 1) ? kl_ : nullptr;
  const int k0 = blockIdx.x * 32, d0 = blockIdx.y * 32;
  const int tx = threadIdx.x, ty = threadIdx.y;
  __shared__ float tile[32][33];
#pragma unroll
  for (int r = 0; r < 4; ++r) {
    const int kl = ty + r * 8;
    tile[kl][tx] = W[(long)(k0 + kl) * DD + d0 + tx];
  }
  __syncthreads();
#pragma unroll
  for (int r = 0; r < 4; ++r) {
    const int dl = ty + r * 8;
    const float v = tile[tx][dl];                // = W[k0+tx][d0+dl]
    const ushort h = f2b(v);
    const long o = (long)(d0 + dl) * KK + k0 + tx;
    Th[o] = h;
    if (Tl) Tl[o] = f2b(v - b2f(h));
  }
}

// ---------------------------------------------------------------------------
// fp32 -> (hi, lo) bf16 elementwise split, vectorized, grid-stride.
// ---------------------------------------------------------------------------
__global__ __launch_bounds__(256) void cvt_split(
    const float* __restrict__ src, ushort* __restrict__ h,
    ushort* __restrict__ l, long n) {
  const long stride = (long)gridDim.x * 256 * 4;
  for (long i = ((long)blockIdx.x * 256 + threadIdx.x) * 4; i < n; i += stride) {
    const float4 v = *(const float4*)(src + i);
    ushort hh[4], ll[4];
    const float vv[4] = {v.x, v.y, v.z, v.w};
#pragma unroll
    for (int u = 0; u < 4; ++u) {
      hh[u] = f2b(vv[u]);
      ll[u] = f2b(vv[u] - b2f(hh[u]));
    }
    *(ushort4*)(h + i) = make_ushort4(hh[0], hh[1], hh[2], hh[3]);
    *(ushort4*)(l + i) = make_ushort4(ll[0], ll[1], ll[2], ll[3]);
  }
}

// ---------------------------------------------------------------------------
// bf16 MFMA GEMM, 128x128 block tile, 4 waves (2x2) of 64x64, BK=32,
// 16x16x32 MFMA, global_load_lds(16B) staging into packed LDS [128][32].
// Fragment layouts (HW-verified, learn_hip m89):
//   A[m=lane&15][k=quad*8+j], B[n=lane&15][k=quad*8+j],
//   C/D: col=lane&15, row=quad*4+reg.
// SPLIT: hi+lo bf16 operands, 3 MFMAs (hh, hl, lh) ~= fp32 accuracy.
// TRIA : A staged from triangular tile layout; K limited to m0+128.
// SPLITK: grid.z = B*SPLITK; each block does K/SPLITK; STOREs 1/4 atomicAdd.
// STORE 0: split bf16 (C0=hi, C1=lo), row-major ldc
//       1: triangular-tile fp32 (grid.x over NTRI lower tiles); atomic if SPLITK>1
//       2: bf16 row-major
//       3: fp32 row-major with residual add from Res
//       4: fp32 row-major atomicAdd (split-K partials)
// ---------------------------------------------------------------------------
template <int SPLIT, int TRIA, int STORE, int SPLITK>
__global__ __launch_bounds__(256) void gemm_mfma(
    const ushort* __restrict__ Ah, const ushort* __restrict__ Al,
    const ushort* __restrict__ Bh, const ushort* __restrict__ Bl,
    void* __restrict__ C0, void* __restrict__ C1, const float* __restrict__ Res,
    int K, int lda, int ldb, int ldc,
    long bA, long bB, long bC, long bR) {
  extern __shared__ ushort smem[];
  ushort* sAh = smem;                                    // [128][32] 8KB
  ushort* sBh = smem + (SPLIT ? 8192 : 4096);
  ushort* sAl = SPLIT ? smem + 4096 : nullptr;
  ushort* sBl = SPLIT ? smem + 12288 : nullptr;

  const int zz = blockIdx.z;
  const int b = zz / SPLITK;
  const int ks = zz % SPLITK;
  int m0, n0, tiC = 0;
  if (STORE == 1) {
    int t = blockIdx.x;
    int ti = 0;
    while ((ti + 1) * (ti + 2) / 2 <= t) ++ti;
    const int tj = t - ti * (ti + 1) / 2;
    m0 = ti * 128; n0 = tj * 128; tiC = t;
  } else {
    m0 = blockIdx.y * 128; n0 = blockIdx.x * 128;
  }
  const int kslice = K / SPLITK;
  const int kbeg = ks * kslice;
  const int kmax = TRIA ? (m0 + 128) : (kbeg + kslice);
  int triA0 = 0;
  if (TRIA) { const int ti = m0 >> 7; triA0 = ti * (ti + 1) / 2; }

  const ushort* A_h = Ah + (long)b * bA;
  const ushort* B_h = Bh + (long)b * bB;
  const ushort* A_l = SPLIT ? Al + (long)b * bA : nullptr;
  const ushort* B_l = SPLIT ? Bl + (long)b * bB : nullptr;

  const int tid = threadIdx.x;
  const int lane = tid & 63, wave = tid >> 6;
  const int wm = (wave & 1) * 64, wn = (wave >> 1) * 64;
  const int r16 = lane & 15, quad = lane >> 4;

  f32x4 acc[4][4];
#pragma unroll
  for (int i = 0; i < 4; ++i)
#pragma unroll
    for (int j = 0; j < 4; ++j) acc[i][j] = (f32x4){0.f, 0.f, 0.f, 0.f};

  for (int k0 = kbeg; k0 < kmax; k0 += 32) {
    __syncthreads();
    {
      const int kc = (lane & 3) * 8;      // k-elems within 32 (16B chunk)
#pragma unroll
      for (int c = 0; c < 2; ++c) {
        const int seg = wave * 2 + c;     // 16-row group 0..7
        const int row = seg * 16 + (lane >> 2);
        long aoff;
        if (TRIA)
          aoff = (long)(triA0 + (k0 >> 7)) * TRI_ELEMS + (long)row * 128 + (k0 & 127) + kc;
        else
          aoff = (long)(m0 + row) * lda + k0 + kc;
        const long boff = (long)(n0 + row) * ldb + k0 + kc;
        async16(A_h + aoff, sAh + seg * 512);
        async16(B_h + boff, sBh + seg * 512);
        if (SPLIT) {
          async16(A_l + aoff, sAl + seg * 512);
          async16(B_l + boff, sBl + seg * 512);
        }
      }
    }
    __syncthreads();

    bfrag ah[4], bh[4], al[4], bl[4];
#pragma unroll
    for (int t4 = 0; t4 < 4; ++t4) {
      ah[t4] = *(const bfrag*)&sAh[(wm + t4 * 16 + r16) * 32 + quad * 8];
      bh[t4] = *(const bfrag*)&sBh[(wn + t4 * 16 + r16) * 32 + quad * 8];
      if (SPLIT) {
        al[t4] = *(const bfrag*)&sAl[(wm + t4 * 16 + r16) * 32 + quad * 8];
        bl[t4] = *(const bfrag*)&sBl[(wn + t4 * 16 + r16) * 32 + quad * 8];
      }
    }
#pragma unroll
    for (int mt = 0; mt < 4; ++mt)
#pragma unroll
      for (int nt = 0; nt < 4; ++nt) {
        acc[mt][nt] = __builtin_amdgcn_mfma_f32_16x16x32_bf16(ah[mt], bh[nt], acc[mt][nt], 0, 0, 0);
        if (SPLIT) {
          acc[mt][nt] = __builtin_amdgcn_mfma_f32_16x16x32_bf16(ah[mt], bl[nt], acc[mt][nt], 0, 0, 0);
          acc[mt][nt] = __builtin_amdgcn_mfma_f32_16x16x32_bf16(al[mt], bh[nt], acc[mt][nt], 0, 0, 0);
        }
      }
  }

  // epilogue
#pragma unroll
  for (int mt = 0; mt < 4; ++mt)
#pragma unroll
    for (int nt = 0; nt < 4; ++nt)
#pragma unroll
      for (int reg = 0; reg < 4; ++reg) {
        const int ml = wm + mt * 16 + quad * 4 + reg;
        const int nl = wn + nt * 16 + r16;
        const float v = acc[mt][nt][reg];
        if (STORE == 0) {
          ushort* Ch = (ushort*)C0 + (long)b * bC;
          ushort* Cl = (ushort*)C1 + (long)b * bC;
          const long o = (long)(m0 + ml) * ldc + n0 + nl;
          const ushort h = f2b(v);
          Ch[o] = h;
          Cl[o] = f2b(v - b2f(h));
        } else if (STORE == 1) {
          float* C = (float*)C0 + (long)b * bC + (long)tiC * TRI_ELEMS;
          if (SPLITK > 1) atomicAdd(&C[ml * 128 + nl], v);
          else C[ml * 128 + nl] = v;
        } else if (STORE == 2) {
          ushort* C = (ushort*)C0 + (long)b * bC;
          C[(long)(m0 + ml) * ldc + n0 + nl] = f2b(v);
        } else if (STORE == 3) {
          float* C = (float*)C0 + (long)b * bC;
          const float* R = Res + (long)b * bR;
          const long o = (long)(m0 + ml) * ldc + n0 + nl;
          C[o] = R[o] + v;
        } else {
          float* C = (float*)C0 + (long)b * bC;
          atomicAdd(&C[(long)(m0 + ml) * ldc + n0 + nl], v);
        }
      }
}

// ---------------------------------------------------------------------------
// Causal softmax over triangular-tiled logits. One block per row (b, i).
// Writes bf16 A in tri layout, zero-filling diagonal-tile cols beyond i.
// ---------------------------------------------------------------------------
__global__ __launch_bounds__(256) void softmax_tri(
    const float* __restrict__ L, ushort* __restrict__ Aout) {
  const int row = blockIdx.x;
  const int b = row >> 11, i = row & (NN - 1);
  const int ti = i >> 7, ml = i & 127;
  const long base = (long)b * ((long)NTRI * TRI_ELEMS);
  const int trib = ti * (ti + 1) / 2;
  const int len = i + 1;
  const int tot = (ti + 1) * 128;
  const int tid = threadIdx.x;
  __shared__ float red[256];
  float vv[8];
  float m = -INFINITY;
#pragma unroll
  for (int u = 0; u < 8; ++u) {
    const int j = tid + u * 256;
    if (j < len) {
      const float v = L[base + (long)(trib + (j >> 7)) * TRI_ELEMS + ml * 128 + (j & 127)];
      vv[u] = v;
      m = fmaxf(m, v);
    }
  }
  red[tid] = m; __syncthreads();
  for (int s = 128; s; s >>= 1) { if (tid < s) red[tid] = fmaxf(red[tid], red[tid + s]); __syncthreads(); }
  m = red[0]; __syncthreads();
  float sum = 0.f;
#pragma unroll
  for (int u = 0; u < 8; ++u) {
    const int j = tid + u * 256;
    if (j < len) { const float e = __expf(vv[u] - m); vv[u] = e; sum += e; }
  }
  red[tid] = sum; __syncthreads();
  for (int s = 128; s; s >>= 1) { if (tid < s) red[tid] += red[tid + s]; __syncthreads(); }
  const float inv = 1.f / red[0];
#pragma unroll
  for (int u = 0; u < 8; ++u) {
    const int j = tid + u * 256;
    if (j < tot) {
      const ushort o = (j < len) ? f2b(vv[u] * inv) : (ushort)0;
      Aout[base + (long)(trib + (j >> 7)) * TRI_ELEMS + ml * 128 + (j & 127)] = o;
    }
  }
}

// ---------------------------------------------------------------------------
// Pipeline (all MFMA operands k-contiguous by construction):
//  0. x -> x_hi [b][d][n], xT hi/lo [b][n][d];  W_Q..W_O -> WT [d][k] bf16
//  1. Mqk = WQT x WKT^T (split MFMA, split store), Mov = WOT x WVT^T (bf16)
//  2. t_f[i,d] = sum_e xT[i,e] Mqk[d,e]   split MFMA, SPLIT-K x2, atomic fp32
//     cvt_split: t_f -> tT hi/lo
//  3. logits[i,j] = sum_d xT[i,d] tT[j,d] split MFMA, SPLIT-K x2, atomic fp32,
//     lower tri tiles
//  4. A = causal softmax (bf16, tri layout, zero-padded diag tiles)
//  5. ctxT[i,e] = sum_{t<=i} A[i,t] x[e,t]      bf16 MFMA, causal K-limit
//  6. out[d,i] = x[d,i] + sum_e Mov[d,e] ctxT[i,e]   bf16 MFMA + residual
// Workspace ~138 MB: t_f / logits / ctxT share the last region.
// ---------------------------------------------------------------------------
extern "C" void kernel_launch(void* const* d_in, const int* in_sizes, int n_in,
                              void* d_out, int out_size, void* d_ws, size_t ws_size,
                              hipStream_t stream) {
  const float* x = (const float*)d_in[0];
  const float* WQ = (const float*)d_in[1];
  const float* WK = (const float*)d_in[2];
  const float* WV = (const float*)d_in[3];
  const float* WO = (const float*)d_in[4];
  float* out = (float*)d_out;

  const long XE = (long)BB * DD * NN;    // 8M elements
  const long WE = (long)DD * KK;         // 1M elements
  ushort* x_hi = (ushort*)d_ws;
  ushort* xTh = x_hi + XE;
  ushort* xTl = xTh + XE;
  ushort* wqT_h = xTl + XE;
  ushort* wqT_l = wqT_h + WE;
  ushort* wkT_h = wqT_l + WE;
  ushort* wkT_l = wkT_h + WE;
  ushort* wvT_h = wkT_l + WE;
  ushort* woT_h = wvT_h + WE;
  ushort* mqk_h = woT_h + WE;
  ushort* mqk_l = mqk_h + WE;
  ushort* mov_h = mqk_l + WE;
  ushort* tTh = mov_h + WE;
  ushort* tTl = tTh + XE;
  float* t_f = (float*)(tTl + XE);       // XE fp32 (33.5MB), split-K partials
  float* logits = t_f;                   // B*NTRI*TRI_ELEMS fp32 (35.7MB), after cvt
  ushort* A_tri = tTh;                   // overlays tT hi+lo (dead after step 3)
  ushort* ctxT = (ushort*)logits;        // overlays logits (dead after softmax)
  const long TRIB = (long)NTRI * TRI_ELEMS;
  const long XB = XE / BB;

  // zero split-K accumulator for t
  hipMemsetAsync(t_f, 0, XE * sizeof(float), stream);

  transpose_split<<<dim3(NN / 32, DD / 32, BB), dim3(32, 8), 0, stream>>>(x, x_hi, xTh, xTl);
  wtrans4<<<dim3(KK / 32, DD / 32, 4), dim3(32, 8), 0, stream>>>(
      WQ, WK, WV, WO, wqT_h, wqT_l, wkT_h, wkT_l, wvT_h, woT_h);

  // Mqk = WQT * WKT^T (split, split store)
  gemm_mfma<1, 0, 0, 1><<<dim3(DD / 128, DD / 128, 1), 256, 32768, stream>>>(
      wqT_h, wqT_l, wkT_h, wkT_l, mqk_h, mqk_l, nullptr,
      KK, KK, KK, DD, 0, 0, 0, 0);
  // Mov = WOT * WVT^T (plain bf16)
  gemm_mfma<0, 0, 2, 1><<<dim3(DD / 128, DD / 128, 1), 256, 16384, stream>>>(
      woT_h, nullptr, wvT_h, nullptr, mov_h, nullptr, nullptr,
      KK, KK, KK, DD, 0, 0, 0, 0);

  // t_f = xT * Mqk^T (split, split-K x2, atomic fp32)
  gemm_mfma<1, 0, 4, 2><<<dim3(DD / 128, NN / 128, BB * 2), 256, 32768, stream>>>(
      xTh, xTl, mqk_h, mqk_l, t_f, nullptr, nullptr,
      DD, DD, DD, DD, XB, 0, XB, 0);

  // tT hi/lo from t_f
  cvt_split<<<dim3(2048), 256, 0, stream>>>(t_f, tTh, tTl, XE);

  // zero logits accumulator (same region as t_f, now dead)
  hipMemsetAsync(logits, 0, TRIB * BB * sizeof(float), stream);

  // logits (lower tri tiles, split-K x2, atomic fp32)
  gemm_mfma<1, 0, 1, 2><<<dim3(NTRI, 1, BB * 2), 256, 32768, stream>>>(
      xTh, xTl, tTh, tTl, logits, nullptr, nullptr,
      DD, DD, DD, 0, XB, XB, TRIB, 0);

  softmax_tri<<<dim3(BB * NN), 256, 0, stream>>>(logits, A_tri);

  // ctxT = A * x^T (tri A, causal K-limit)
  gemm_mfma<0, 1, 2, 1><<<dim3(DD / 128, NN / 128, BB), 256, 16384, stream>>>(
      A_tri, nullptr, x_hi, nullptr, ctxT, nullptr, nullptr,
      NN, 0, NN, DD, TRIB, XB, XB, 0);

  // out = x + Mov * ctx
  gemm_mfma<0, 0, 3, 1><<<dim3(NN / 128, DD / 128, BB), 256, 16384, stream>>>(
      mov_h, nullptr, ctxT, nullptr, out, nullptr, x,
      DD, DD, DD, NN, 0, XB, XB, XB);
}

// Round 5
// 391.633 us; speedup vs baseline: 1.3064x; 1.3064x over previous
//
#include <hip/hip_runtime.h>
#include <hip/hip_bf16.h>
#include <math.h>

// Problem constants: B=4, D=1024, N=2048, K=1024, fp32 in/out.
#define BB 4
#define DD 1024
#define NN 2048
#define KK 1024
#define NT128 16            // NN/128
#define NTRI 136            // 16*17/2 lower-triangular 128x128 tiles
#define TRI_ELEMS 16384     // 128*128

typedef __attribute__((ext_vector_type(4))) float f32x4;
typedef __attribute__((ext_vector_type(8))) short bfrag;

typedef __attribute__((address_space(1))) const unsigned int gu32;
typedef __attribute__((address_space(3))) unsigned int lu32;

// async global->LDS, 16B per lane; LDS dest = base + lane*16 (wave-uniform base)
__device__ __forceinline__ void async16(const void* g, void* l) {
  __builtin_amdgcn_global_load_lds((gu32*)g, (lu32*)l, 16, 0, 0);
}

__device__ __forceinline__ ushort f2b(float f) {  // fp32 -> bf16 RNE
  union { float f; unsigned u; } c; c.f = f;
  unsigned u = c.u + 0x7fffu + ((c.u >> 16) & 1u);
  return (ushort)(u >> 16);
}
__device__ __forceinline__ float b2f(ushort h) {
  union { unsigned u; float f; } c; c.u = ((unsigned)h) << 16;
  return c.f;
}

// ---------------------------------------------------------------------------
// x [b][d][n] fp32 -> x_hi (bf16, same layout), xT_hi/xT_lo (bf16, [b][n][d])
// ---------------------------------------------------------------------------
__global__ __launch_bounds__(256) void transpose_split(
    const float* __restrict__ x, ushort* __restrict__ xhi,
    ushort* __restrict__ xTh, ushort* __restrict__ xTl) {
  const int b = blockIdx.z;
  const int n0 = blockIdx.x * 32, d0 = blockIdx.y * 32;
  const int tx = threadIdx.x, ty = threadIdx.y;
  __shared__ float tile[32][33];
  const float* xb = x + (long)b * DD * NN;
  ushort* xhb = xhi + (long)b * DD * NN;
#pragma unroll
  for (int r = 0; r < 4; ++r) {
    const int dl = ty + r * 8;
    const float v = xb[(long)(d0 + dl) * NN + n0 + tx];
    tile[dl][tx] = v;
    xhb[(long)(d0 + dl) * NN + n0 + tx] = f2b(v);
  }
  __syncthreads();
#pragma unroll
  for (int r = 0; r < 4; ++r) {
    const int nl = ty + r * 8;
    const float v = tile[tx][nl];
    const ushort h = f2b(v);
    const long o = (long)b * NN * DD + (long)(n0 + nl) * DD + d0 + tx;
    xTh[o] = h;
    xTl[o] = f2b(v - b2f(h));
  }
}

// ---------------------------------------------------------------------------
// All four weight transposes in ONE dispatch. z selects W; z<2 also writes lo.
// W (K x D fp32, row-major [k][d]) -> WT [d][k] bf16.
// ---------------------------------------------------------------------------
__global__ __launch_bounds__(256) void wtrans4(
    const float* __restrict__ WQ, const float* __restrict__ WK,
    const float* __restrict__ WV, const float* __restrict__ WO,
    ushort* __restrict__ qh, ushort* __restrict__ ql,
    ushort* __restrict__ kh, ushort* __restrict__ kl_,
    ushort* __restrict__ vh, ushort* __restrict__ oh) {
  const int z = blockIdx.z;
  const float* W = (z == 0) ? WQ : (z == 1) ? WK : (z == 2) ? WV : WO;
  ushort* Th = (z == 0) ? qh : (z == 1) ? kh : (z == 2) ? vh : oh;
  ushort* Tl = (z == 0) ? ql : (z == 1) ? kl_ : nullptr;
  const int k0 = blockIdx.x * 32, d0 = blockIdx.y * 32;
  const int tx = threadIdx.x, ty = threadIdx.y;
  __shared__ float tile[32][33];
#pragma unroll
  for (int r = 0; r < 4; ++r) {
    const int kl = ty + r * 8;
    tile[kl][tx] = W[(long)(k0 + kl) * DD + d0 + tx];
  }
  __syncthreads();
#pragma unroll
  for (int r = 0; r < 4; ++r) {
    const int dl = ty + r * 8;
    const float v = tile[tx][dl];                // = W[k0+tx][d0+dl]
    const ushort h = f2b(v);
    const long o = (long)(d0 + dl) * KK + k0 + tx;
    Th[o] = h;
    if (Tl) Tl[o] = f2b(v - b2f(h));
  }
}

// ---------------------------------------------------------------------------
// bf16 MFMA GEMM, 128x128 block tile, 4 waves (2x2) of 64x64, BK=32,
// 16x16x32 MFMA, global_load_lds(16B) staging into packed LDS [128][32].
// Fragment layouts (HW-verified, learn_hip m89):
//   A[m=lane&15][k=quad*8+j], B[n=lane&15][k=quad*8+j],
//   C/D: col=lane&15, row=quad*4+reg.
// SPLIT: hi+lo bf16 operands, 3 MFMAs (hh, hl, lh) ~= fp32 accuracy.
// TRIA : A staged from triangular tile layout; K limited to m0+128.
// SWIZ : XCD-locality block mapping (assumes xcd = blockIdx.x % 8):
//   0: plain 2-D grid (blockIdx.{x,y,z})
//   1: 1-D grid of 512, g=(blk&7)*64+(blk>>3); P=g>>3 -> (b=P>>4, m0=(P&15)*128),
//      n0=(g&7)*128. Each XCD owns 8 consecutive (b,i) A-tiles x all 8 n-tiles,
//      so concurrent blocks on one XCD share A rows and the full B panel.
//   2: 1-D grid of 544 (logits tri), g=(blk&7)*68+(blk>>3); b=g/136,
//      t=g%136 -> (ti,tj). Contiguous tri runs share A rows / B cols per XCD.
// STORE 0: split bf16 (C0=hi, C1=lo), row-major ldc
//       1: triangular-tile fp32
//       2: bf16 row-major
//       3: fp32 row-major with residual add from Res
// ---------------------------------------------------------------------------
template <int SPLIT, int TRIA, int STORE, int SWIZ>
__global__ __launch_bounds__(256) void gemm_mfma(
    const ushort* __restrict__ Ah, const ushort* __restrict__ Al,
    const ushort* __restrict__ Bh, const ushort* __restrict__ Bl,
    void* __restrict__ C0, void* __restrict__ C1, const float* __restrict__ Res,
    int K, int lda, int ldb, int ldc,
    long bA, long bB, long bC, long bR) {
  extern __shared__ ushort smem[];
  ushort* sAh = smem;                                    // [128][32] 8KB
  ushort* sBh = smem + (SPLIT ? 8192 : 4096);
  ushort* sAl = SPLIT ? smem + 4096 : nullptr;
  ushort* sBl = SPLIT ? smem + 12288 : nullptr;

  int b, m0, n0, tiC = 0;
  if (SWIZ == 2) {
    const int g = (blockIdx.x & 7) * 68 + (blockIdx.x >> 3);
    b = g / NTRI;
    int t = g - b * NTRI;
    int ti = 0;
    while ((ti + 1) * (ti + 2) / 2 <= t) ++ti;
    const int tj = t - ti * (ti + 1) / 2;
    m0 = ti * 128; n0 = tj * 128; tiC = t;
  } else if (SWIZ == 1) {
    const int g = (blockIdx.x & 7) * 64 + (blockIdx.x >> 3);
    const int P = g >> 3;
    b = P >> 4;
    m0 = (P & 15) * 128;
    n0 = (g & 7) * 128;
  } else {
    b = blockIdx.z; m0 = blockIdx.y * 128; n0 = blockIdx.x * 128;
  }
  const int kmax = TRIA ? (m0 + 128) : K;
  int triA0 = 0;
  if (TRIA) { const int ti = m0 >> 7; triA0 = ti * (ti + 1) / 2; }

  const ushort* A_h = Ah + (long)b * bA;
  const ushort* B_h = Bh + (long)b * bB;
  const ushort* A_l = SPLIT ? Al + (long)b * bA : nullptr;
  const ushort* B_l = SPLIT ? Bl + (long)b * bB : nullptr;

  const int tid = threadIdx.x;
  const int lane = tid & 63, wave = tid >> 6;
  const int wm = (wave & 1) * 64, wn = (wave >> 1) * 64;
  const int r16 = lane & 15, quad = lane >> 4;

  f32x4 acc[4][4];
#pragma unroll
  for (int i = 0; i < 4; ++i)
#pragma unroll
    for (int j = 0; j < 4; ++j) acc[i][j] = (f32x4){0.f, 0.f, 0.f, 0.f};

  for (int k0 = 0; k0 < kmax; k0 += 32) {
    __syncthreads();
    {
      const int kc = (lane & 3) * 8;      // k-elems within 32 (16B chunk)
#pragma unroll
      for (int c = 0; c < 2; ++c) {
        const int seg = wave * 2 + c;     // 16-row group 0..7
        const int row = seg * 16 + (lane >> 2);
        long aoff;
        if (TRIA)
          aoff = (long)(triA0 + (k0 >> 7)) * TRI_ELEMS + (long)row * 128 + (k0 & 127) + kc;
        else
          aoff = (long)(m0 + row) * lda + k0 + kc;
        const long boff = (long)(n0 + row) * ldb + k0 + kc;
        async16(A_h + aoff, sAh + seg * 512);
        async16(B_h + boff, sBh + seg * 512);
        if (SPLIT) {
          async16(A_l + aoff, sAl + seg * 512);
          async16(B_l + boff, sBl + seg * 512);
        }
      }
    }
    __syncthreads();

    bfrag ah[4], bh[4], al[4], bl[4];
#pragma unroll
    for (int t4 = 0; t4 < 4; ++t4) {
      ah[t4] = *(const bfrag*)&sAh[(wm + t4 * 16 + r16) * 32 + quad * 8];
      bh[t4] = *(const bfrag*)&sBh[(wn + t4 * 16 + r16) * 32 + quad * 8];
      if (SPLIT) {
        al[t4] = *(const bfrag*)&sAl[(wm + t4 * 16 + r16) * 32 + quad * 8];
        bl[t4] = *(const bfrag*)&sBl[(wn + t4 * 16 + r16) * 32 + quad * 8];
      }
    }
#pragma unroll
    for (int mt = 0; mt < 4; ++mt)
#pragma unroll
      for (int nt = 0; nt < 4; ++nt) {
        acc[mt][nt] = __builtin_amdgcn_mfma_f32_16x16x32_bf16(ah[mt], bh[nt], acc[mt][nt], 0, 0, 0);
        if (SPLIT) {
          acc[mt][nt] = __builtin_amdgcn_mfma_f32_16x16x32_bf16(ah[mt], bl[nt], acc[mt][nt], 0, 0, 0);
          acc[mt][nt] = __builtin_amdgcn_mfma_f32_16x16x32_bf16(al[mt], bh[nt], acc[mt][nt], 0, 0, 0);
        }
      }
  }

  // epilogue
#pragma unroll
  for (int mt = 0; mt < 4; ++mt)
#pragma unroll
    for (int nt = 0; nt < 4; ++nt)
#pragma unroll
      for (int reg = 0; reg < 4; ++reg) {
        const int ml = wm + mt * 16 + quad * 4 + reg;
        const int nl = wn + nt * 16 + r16;
        const float v = acc[mt][nt][reg];
        if (STORE == 0) {
          ushort* Ch = (ushort*)C0 + (long)b * bC;
          ushort* Cl = (ushort*)C1 + (long)b * bC;
          const long o = (long)(m0 + ml) * ldc + n0 + nl;
          const ushort h = f2b(v);
          Ch[o] = h;
          Cl[o] = f2b(v - b2f(h));
        } else if (STORE == 1) {
          float* C = (float*)C0 + (long)b * bC + (long)tiC * TRI_ELEMS;
          C[ml * 128 + nl] = v;
        } else if (STORE == 2) {
          ushort* C = (ushort*)C0 + (long)b * bC;
          C[(long)(m0 + ml) * ldc + n0 + nl] = f2b(v);
        } else {
          float* C = (float*)C0 + (long)b * bC;
          const float* R = Res + (long)b * bR;
          const long o = (long)(m0 + ml) * ldc + n0 + nl;
          C[o] = R[o] + v;
        }
      }
}

// ---------------------------------------------------------------------------
// Causal softmax over triangular-tiled logits. One block per row (b, i).
// Writes bf16 A in tri layout, zero-filling diagonal-tile cols beyond i.
// ---------------------------------------------------------------------------
__global__ __launch_bounds__(256) void softmax_tri(
    const float* __restrict__ L, ushort* __restrict__ Aout) {
  const int row = blockIdx.x;
  const int b = row >> 11, i = row & (NN - 1);
  const int ti = i >> 7, ml = i & 127;
  const long base = (long)b * ((long)NTRI * TRI_ELEMS);
  const int trib = ti * (ti + 1) / 2;
  const int len = i + 1;
  const int tot = (ti + 1) * 128;
  const int tid = threadIdx.x;
  __shared__ float red[256];
  float vv[8];
  float m = -INFINITY;
#pragma unroll
  for (int u = 0; u < 8; ++u) {
    const int j = tid + u * 256;
    if (j < len) {
      const float v = L[base + (long)(trib + (j >> 7)) * TRI_ELEMS + ml * 128 + (j & 127)];
      vv[u] = v;
      m = fmaxf(m, v);
    }
  }
  red[tid] = m; __syncthreads();
  for (int s = 128; s; s >>= 1) { if (tid < s) red[tid] = fmaxf(red[tid], red[tid + s]); __syncthreads(); }
  m = red[0]; __syncthreads();
  float sum = 0.f;
#pragma unroll
  for (int u = 0; u < 8; ++u) {
    const int j = tid + u * 256;
    if (j < len) { const float e = __expf(vv[u] - m); vv[u] = e; sum += e; }
  }
  red[tid] = sum; __syncthreads();
  for (int s = 128; s; s >>= 1) { if (tid < s) red[tid] += red[tid + s]; __syncthreads(); }
  const float inv = 1.f / red[0];
#pragma unroll
  for (int u = 0; u < 8; ++u) {
    const int j = tid + u * 256;
    if (j < tot) {
      const ushort o = (j < len) ? f2b(vv[u] * inv) : (ushort)0;
      Aout[base + (long)(trib + (j >> 7)) * TRI_ELEMS + ml * 128 + (j & 127)] = o;
    }
  }
}

// ---------------------------------------------------------------------------
// Pipeline (all MFMA operands k-contiguous by construction):
//  0. x -> x_hi [b][d][n], xT hi/lo [b][n][d];  W_Q..W_O -> WT [d][k] bf16
//  1. Mqk = WQT x WKT^T (split MFMA, split store), Mov = WOT x WVT^T (bf16)
//  2. tT[i,d] = sum_e xT[i,e] Mqk[d,e]      split MFMA, split store, SWIZ=1
//  3. logits[i,j] = sum_d xT[i,d] tT[j,d]   split MFMA, tri tiles, SWIZ=2
//  4. A = causal softmax (bf16, tri layout, zero-padded diag tiles)
//  5. ctxT[i,e] = sum_{t<=i} A[i,t] x[e,t]  bf16 MFMA, causal K-limit, SWIZ=1
//  6. out[d,i] = x[d,i] + sum_e Mov[d,e] ctxT[i,e]   bf16 MFMA + residual
// ---------------------------------------------------------------------------
extern "C" void kernel_launch(void* const* d_in, const int* in_sizes, int n_in,
                              void* d_out, int out_size, void* d_ws, size_t ws_size,
                              hipStream_t stream) {
  const float* x = (const float*)d_in[0];
  const float* WQ = (const float*)d_in[1];
  const float* WK = (const float*)d_in[2];
  const float* WV = (const float*)d_in[3];
  const float* WO = (const float*)d_in[4];
  float* out = (float*)d_out;

  const long XE = (long)BB * DD * NN;    // 8M elements
  const long WE = (long)DD * KK;         // 1M elements
  ushort* x_hi = (ushort*)d_ws;
  ushort* xTh = x_hi + XE;
  ushort* xTl = xTh + XE;
  ushort* wqT_h = xTl + XE;
  ushort* wqT_l = wqT_h + WE;
  ushort* wkT_h = wqT_l + WE;
  ushort* wkT_l = wkT_h + WE;
  ushort* wvT_h = wkT_l + WE;
  ushort* woT_h = wvT_h + WE;
  ushort* mqk_h = woT_h + WE;
  ushort* mqk_l = mqk_h + WE;
  ushort* mov_h = mqk_l + WE;
  ushort* tTh = mov_h + WE;
  ushort* tTl = tTh + XE;
  float* logits = (float*)(tTl + XE);    // B*NTRI*TRI_ELEMS fp32 (~35.7MB)
  ushort* A_tri = tTh;                   // overlays tT hi+lo (dead after step 3)
  ushort* ctxT = (ushort*)logits;        // overlays logits (dead after softmax)
  const long TRIB = (long)NTRI * TRI_ELEMS;
  const long XB = XE / BB;

  transpose_split<<<dim3(NN / 32, DD / 32, BB), dim3(32, 8), 0, stream>>>(x, x_hi, xTh, xTl);
  wtrans4<<<dim3(KK / 32, DD / 32, 4), dim3(32, 8), 0, stream>>>(
      WQ, WK, WV, WO, wqT_h, wqT_l, wkT_h, wkT_l, wvT_h, woT_h);

  // Mqk = WQT * WKT^T (split, split store)
  gemm_mfma<1, 0, 0, 0><<<dim3(DD / 128, DD / 128, 1), 256, 32768, stream>>>(
      wqT_h, wqT_l, wkT_h, wkT_l, mqk_h, mqk_l, nullptr,
      KK, KK, KK, DD, 0, 0, 0, 0);
  // Mov = WOT * WVT^T (plain bf16)
  gemm_mfma<0, 0, 2, 0><<<dim3(DD / 128, DD / 128, 1), 256, 16384, stream>>>(
      woT_h, nullptr, wvT_h, nullptr, mov_h, nullptr, nullptr,
      KK, KK, KK, DD, 0, 0, 0, 0);

  // tT = xT * Mqk^T (split, XCD-swizzled 1-D grid)
  gemm_mfma<1, 0, 0, 1><<<dim3(512), 256, 32768, stream>>>(
      xTh, xTl, mqk_h, mqk_l, tTh, tTl, nullptr,
      DD, DD, DD, DD, XB, 0, XB, 0);

  // logits (lower tri tiles, XCD-swizzled 1-D grid)
  gemm_mfma<1, 0, 1, 2><<<dim3(BB * NTRI), 256, 32768, stream>>>(
      xTh, xTl, tTh, tTl, logits, nullptr, nullptr,
      DD, DD, DD, 0, XB, XB, TRIB, 0);

  softmax_tri<<<dim3(BB * NN), 256, 0, stream>>>(logits, A_tri);

  // ctxT = A * x^T (tri A, causal K-limit, XCD-swizzled 1-D grid)
  gemm_mfma<0, 1, 2, 1><<<dim3(512), 256, 16384, stream>>>(
      A_tri, nullptr, x_hi, nullptr, ctxT, nullptr, nullptr,
      NN, 0, NN, DD, TRIB, XB, XB, 0);

  // out = x + Mov * ctx
  gemm_mfma<0, 0, 3, 0><<<dim3(NN / 128, DD / 128, BB), 256, 16384, stream>>>(
      mov_h, nullptr, ctxT, nullptr, out, nullptr, x,
      DD, DD, DD, NN, 0, XB, XB, XB);
}

// Round 6
// 352.936 us; speedup vs baseline: 1.4496x; 1.1096x over previous
//
#include <hip/hip_runtime.h>
#include <hip/hip_bf16.h>
#include <math.h>

// Problem constants: B=4, D=1024, N=2048, K=1024, fp32 in/out.
#define BB 4
#define DD 1024
#define NN 2048
#define KK 1024
#define NT128 16            // NN/128
#define NTRI 136            // 16*17/2 lower-triangular 128x128 tiles
#define TRI_ELEMS 16384     // 128*128

typedef __attribute__((ext_vector_type(4))) float f32x4;
typedef __attribute__((ext_vector_type(8))) short bfrag;

typedef __attribute__((address_space(1))) const unsigned int gu32;
typedef __attribute__((address_space(3))) unsigned int lu32;

// async global->LDS, 16B per lane; LDS dest = base + lane*16 (wave-uniform base)
__device__ __forceinline__ void async16(const void* g, void* l) {
  __builtin_amdgcn_global_load_lds((gu32*)g, (lu32*)l, 16, 0, 0);
}

__device__ __forceinline__ ushort f2b(float f) {  // fp32 -> bf16 RNE
  union { float f; unsigned u; } c; c.f = f;
  unsigned u = c.u + 0x7fffu + ((c.u >> 16) & 1u);
  return (ushort)(u >> 16);
}
__device__ __forceinline__ float b2f(ushort h) {
  union { unsigned u; float f; } c; c.u = ((unsigned)h) << 16;
  return c.f;
}

// ---------------------------------------------------------------------------
// LDS bank-conflict XOR swizzle. LDS tiles are [rows][32] bf16 (row = 64B =
// 16 banks, so unswizzled frag reads alias every 2 rows). We permute which
// 8-elem k-chunk lives in each 16B slot: physical_chunk = logical ^ ((row>>1)&3).
// global_load_lds fixes lane->slot, so the STAGE side permutes the global
// source chunk; the READ side applies the same XOR. Max aliasing becomes
// 2-way, which is free (m136).
//   stage: lane kc = ((lane&3) ^ ((lane>>3)&3)) * 8   [(lane>>3)&3 == (row>>1)&3]
//   read : col = (quad ^ ((r16>>1)&3)) * 8            [row ≡ r16 mod 16]
// ---------------------------------------------------------------------------

// ---------------------------------------------------------------------------
// prep: merged input transform, grid (64, 32, 6), block (32,8).
//  z<4 : x [b=z][d][n] fp32 -> x_hi (bf16 same layout), xT hi/lo ([b][n][d])
//  z>=4: weight w = (z-4)*2 + (bx>>5): W (K x D, [k][d]) -> WT [d][k] bf16
//        (WQ, WK split hi+lo; WV, WO hi only)
// ---------------------------------------------------------------------------
__global__ __launch_bounds__(256) void prep(
    const float* __restrict__ x,
    const float* __restrict__ WQ, const float* __restrict__ WK,
    const float* __restrict__ WV, const float* __restrict__ WO,
    ushort* __restrict__ xhi, ushort* __restrict__ xTh, ushort* __restrict__ xTl,
    ushort* __restrict__ qh, ushort* __restrict__ ql,
    ushort* __restrict__ kh, ushort* __restrict__ kl_,
    ushort* __restrict__ vh, ushort* __restrict__ oh) {
  const int z = blockIdx.z;
  const int tx = threadIdx.x, ty = threadIdx.y;
  __shared__ float tile[32][33];
  if (z < 4) {
    const int b = z;
    const int n0 = blockIdx.x * 32, d0 = blockIdx.y * 32;
    const float* xb = x + (long)b * DD * NN;
    ushort* xhb = xhi + (long)b * DD * NN;
#pragma unroll
    for (int r = 0; r < 4; ++r) {
      const int dl = ty + r * 8;
      const float v = xb[(long)(d0 + dl) * NN + n0 + tx];
      tile[dl][tx] = v;
      xhb[(long)(d0 + dl) * NN + n0 + tx] = f2b(v);
    }
    __syncthreads();
#pragma unroll
    for (int r = 0; r < 4; ++r) {
      const int nl = ty + r * 8;
      const float v = tile[tx][nl];
      const ushort h = f2b(v);
      const long o = (long)b * NN * DD + (long)(n0 + nl) * DD + d0 + tx;
      xTh[o] = h;
      xTl[o] = f2b(v - b2f(h));
    }
  } else {
    const int w = (z - 4) * 2 + (blockIdx.x >> 5);
    const float* W = (w == 0) ? WQ : (w == 1) ? WK : (w == 2) ? WV : WO;
    ushort* Th = (w == 0) ? qh : (w == 1) ? kh : (w == 2) ? vh : oh;
    ushort* Tl = (w == 0) ? ql : (w == 1) ? kl_ : nullptr;
    const int k0 = (blockIdx.x & 31) * 32, d0 = blockIdx.y * 32;
#pragma unroll
    for (int r = 0; r < 4; ++r) {
      const int kl = ty + r * 8;
      tile[kl][tx] = W[(long)(k0 + kl) * DD + d0 + tx];
    }
    __syncthreads();
#pragma unroll
    for (int r = 0; r < 4; ++r) {
      const int dl = ty + r * 8;
      const float v = tile[tx][dl];              // = W[k0+tx][d0+dl]
      const ushort h = f2b(v);
      const long o = (long)(d0 + dl) * KK + k0 + tx;
      Th[o] = h;
      if (Tl) Tl[o] = f2b(v - b2f(h));
    }
  }
}

// ---------------------------------------------------------------------------
// Merged weight-product GEMM, 64x64 tiles, 512 blocks:
//   id<256 : Mqk[m,n] = sum_k wqT[m,k] wkT[n,k]  (split 3-MFMA, split store)
//   id>=256: Mov[m,n] = sum_k woT[m,k] wvT[n,k]  (plain bf16)
// 4 waves in 2x2, each 32x32 (2x2 16x16x32 frags), BK=32.
// ---------------------------------------------------------------------------
__global__ __launch_bounds__(256) void gemm_w(
    const ushort* __restrict__ qh, const ushort* __restrict__ ql,
    const ushort* __restrict__ kh, const ushort* __restrict__ kl_,
    const ushort* __restrict__ vh, const ushort* __restrict__ oh,
    ushort* __restrict__ mqk_h, ushort* __restrict__ mqk_l,
    ushort* __restrict__ mov_h) {
  extern __shared__ ushort smem[];
  ushort* sAh = smem;            // [64][32] 4KB
  ushort* sAl = smem + 2048;
  ushort* sBh = smem + 4096;
  ushort* sBl = smem + 6144;

  const int id = blockIdx.x;
  const int half = id >> 8;                  // 0 = Mqk (split), 1 = Mov (plain)
  const int t = id & 255;
  const int m0 = (t >> 4) * 64, n0 = (t & 15) * 64;
  const ushort* A_h = half ? oh : qh;
  const ushort* B_h = half ? vh : kh;

  const int tid = threadIdx.x;
  const int lane = tid & 63, wave = tid >> 6;
  const int wm = (wave & 1) * 32, wn = (wave >> 1) * 32;
  const int r16 = lane & 15, quad = lane >> 4;
  const int kc = ((lane & 3) ^ ((lane >> 3) & 3)) * 8;   // swizzled k-chunk
  const int srow = lane >> 2;

  f32x4 acc[2][2];
#pragma unroll
  for (int i = 0; i < 2; ++i)
#pragma unroll
    for (int j = 0; j < 2; ++j) acc[i][j] = (f32x4){0.f, 0.f, 0.f, 0.f};

  for (int k0 = 0; k0 < KK; k0 += 32) {
    __syncthreads();
    {
      const int row = wave * 16 + srow;
      const long aoff = (long)(m0 + row) * KK + k0 + kc;
      const long boff = (long)(n0 + row) * KK + k0 + kc;
      async16(A_h + aoff, sAh + wave * 512);
      async16(B_h + boff, sBh + wave * 512);
      if (half == 0) {
        async16(ql + aoff, sAl + wave * 512);
        async16(kl_ + boff, sBl + wave * 512);
      }
    }
    __syncthreads();

    const int sw = (r16 >> 1) & 3;
    bfrag ah[2], bh[2], al[2], bl[2];
#pragma unroll
    for (int t2 = 0; t2 < 2; ++t2) {
      ah[t2] = *(const bfrag*)&sAh[(wm + t2 * 16 + r16) * 32 + (quad ^ sw) * 8];
      bh[t2] = *(const bfrag*)&sBh[(wn + t2 * 16 + r16) * 32 + (quad ^ sw) * 8];
      if (half == 0) {
        al[t2] = *(const bfrag*)&sAl[(wm + t2 * 16 + r16) * 32 + (quad ^ sw) * 8];
        bl[t2] = *(const bfrag*)&sBl[(wn + t2 * 16 + r16) * 32 + (quad ^ sw) * 8];
      }
    }
#pragma unroll
    for (int mt = 0; mt < 2; ++mt)
#pragma unroll
      for (int nt = 0; nt < 2; ++nt) {
        acc[mt][nt] = __builtin_amdgcn_mfma_f32_16x16x32_bf16(ah[mt], bh[nt], acc[mt][nt], 0, 0, 0);
        if (half == 0) {
          acc[mt][nt] = __builtin_amdgcn_mfma_f32_16x16x32_bf16(ah[mt], bl[nt], acc[mt][nt], 0, 0, 0);
          acc[mt][nt] = __builtin_amdgcn_mfma_f32_16x16x32_bf16(al[mt], bh[nt], acc[mt][nt], 0, 0, 0);
        }
      }
  }

#pragma unroll
  for (int mt = 0; mt < 2; ++mt)
#pragma unroll
    for (int nt = 0; nt < 2; ++nt)
#pragma unroll
      for (int reg = 0; reg < 4; ++reg) {
        const int ml = wm + mt * 16 + quad * 4 + reg;
        const int nl = wn + nt * 16 + r16;
        const float v = acc[mt][nt][reg];
        const long o = (long)(m0 + ml) * DD + n0 + nl;
        if (half == 0) {
          const ushort h = f2b(v);
          mqk_h[o] = h;
          mqk_l[o] = f2b(v - b2f(h));
        } else {
          mov_h[o] = f2b(v);
        }
      }
}

// ---------------------------------------------------------------------------
// bf16 MFMA GEMM, 128x128 block tile, 4 waves (2x2) of 64x64, BK=32,
// 16x16x32 MFMA, global_load_lds(16B) staging into swizzled LDS [128][32].
// Fragment layouts (HW-verified, learn_hip m89):
//   A[m=lane&15][k=quad*8+j], B[n=lane&15][k=quad*8+j],
//   C/D: col=lane&15, row=quad*4+reg.
// SPLIT: hi+lo bf16 operands, 3 MFMAs (hh, hl, lh) ~= fp32 accuracy.
// TRIA : A staged from triangular tile layout; K limited to m0+128.
// SWIZ : XCD-locality block mapping (assumes xcd = blockIdx.x % 8):
//   0: plain 2-D grid (blockIdx.{x,y,z})
//   1: 1-D grid of 512, g=(blk&7)*64+(blk>>3); P=g>>3 -> (b=P>>4, m0=(P&15)*128),
//      n0=(g&7)*128.
//   2: 1-D grid of 544 (logits tri), g=(blk&7)*68+(blk>>3); b=g/136,
//      t=g%136 -> (ti,tj).
// STORE 0: split bf16 (C0=hi, C1=lo), row-major ldc
//       1: triangular-tile fp32
//       2: bf16 row-major
//       3: fp32 row-major with residual add from Res
// ---------------------------------------------------------------------------
template <int SPLIT, int TRIA, int STORE, int SWIZ>
__global__ __launch_bounds__(256) void gemm_mfma(
    const ushort* __restrict__ Ah, const ushort* __restrict__ Al,
    const ushort* __restrict__ Bh, const ushort* __restrict__ Bl,
    void* __restrict__ C0, void* __restrict__ C1, const float* __restrict__ Res,
    int K, int lda, int ldb, int ldc,
    long bA, long bB, long bC, long bR) {
  extern __shared__ ushort smem[];
  ushort* sAh = smem;                                    // [128][32] 8KB
  ushort* sBh = smem + (SPLIT ? 8192 : 4096);
  ushort* sAl = SPLIT ? smem + 4096 : nullptr;
  ushort* sBl = SPLIT ? smem + 12288 : nullptr;

  int b, m0, n0, tiC = 0;
  if (SWIZ == 2) {
    const int g = (blockIdx.x & 7) * 68 + (blockIdx.x >> 3);
    b = g / NTRI;
    int t = g - b * NTRI;
    int ti = 0;
    while ((ti + 1) * (ti + 2) / 2 <= t) ++ti;
    const int tj = t - ti * (ti + 1) / 2;
    m0 = ti * 128; n0 = tj * 128; tiC = t;
  } else if (SWIZ == 1) {
    const int g = (blockIdx.x & 7) * 64 + (blockIdx.x >> 3);
    const int P = g >> 3;
    b = P >> 4;
    m0 = (P & 15) * 128;
    n0 = (g & 7) * 128;
  } else {
    b = blockIdx.z; m0 = blockIdx.y * 128; n0 = blockIdx.x * 128;
  }
  const int kmax = TRIA ? (m0 + 128) : K;
  int triA0 = 0;
  if (TRIA) { const int ti = m0 >> 7; triA0 = ti * (ti + 1) / 2; }

  const ushort* A_h = Ah + (long)b * bA;
  const ushort* B_h = Bh + (long)b * bB;
  const ushort* A_l = SPLIT ? Al + (long)b * bA : nullptr;
  const ushort* B_l = SPLIT ? Bl + (long)b * bB : nullptr;

  const int tid = threadIdx.x;
  const int lane = tid & 63, wave = tid >> 6;
  const int wm = (wave & 1) * 64, wn = (wave >> 1) * 64;
  const int r16 = lane & 15, quad = lane >> 4;
  const int kc = ((lane & 3) ^ ((lane >> 3) & 3)) * 8;   // swizzled k-chunk

  f32x4 acc[4][4];
#pragma unroll
  for (int i = 0; i < 4; ++i)
#pragma unroll
    for (int j = 0; j < 4; ++j) acc[i][j] = (f32x4){0.f, 0.f, 0.f, 0.f};

  for (int k0 = 0; k0 < kmax; k0 += 32) {
    __syncthreads();
    {
#pragma unroll
      for (int c = 0; c < 2; ++c) {
        const int seg = wave * 2 + c;     // 16-row group 0..7
        const int row = seg * 16 + (lane >> 2);
        long aoff;
        if (TRIA)
          aoff = (long)(triA0 + (k0 >> 7)) * TRI_ELEMS + (long)row * 128 + (k0 & 127) + kc;
        else
          aoff = (long)(m0 + row) * lda + k0 + kc;
        const long boff = (long)(n0 + row) * ldb + k0 + kc;
        async16(A_h + aoff, sAh + seg * 512);
        async16(B_h + boff, sBh + seg * 512);
        if (SPLIT) {
          async16(A_l + aoff, sAl + seg * 512);
          async16(B_l + boff, sBl + seg * 512);
        }
      }
    }
    __syncthreads();

    const int sw = (r16 >> 1) & 3;
    bfrag ah[4], bh[4], al[4], bl[4];
#pragma unroll
    for (int t4 = 0; t4 < 4; ++t4) {
      ah[t4] = *(const bfrag*)&sAh[(wm + t4 * 16 + r16) * 32 + (quad ^ sw) * 8];
      bh[t4] = *(const bfrag*)&sBh[(wn + t4 * 16 + r16) * 32 + (quad ^ sw) * 8];
      if (SPLIT) {
        al[t4] = *(const bfrag*)&sAl[(wm + t4 * 16 + r16) * 32 + (quad ^ sw) * 8];
        bl[t4] = *(const bfrag*)&sBl[(wn + t4 * 16 + r16) * 32 + (quad ^ sw) * 8];
      }
    }
#pragma unroll
    for (int mt = 0; mt < 4; ++mt)
#pragma unroll
      for (int nt = 0; nt < 4; ++nt) {
        acc[mt][nt] = __builtin_amdgcn_mfma_f32_16x16x32_bf16(ah[mt], bh[nt], acc[mt][nt], 0, 0, 0);
        if (SPLIT) {
          acc[mt][nt] = __builtin_amdgcn_mfma_f32_16x16x32_bf16(ah[mt], bl[nt], acc[mt][nt], 0, 0, 0);
          acc[mt][nt] = __builtin_amdgcn_mfma_f32_16x16x32_bf16(al[mt], bh[nt], acc[mt][nt], 0, 0, 0);
        }
      }
  }

  // epilogue
#pragma unroll
  for (int mt = 0; mt < 4; ++mt)
#pragma unroll
    for (int nt = 0; nt < 4; ++nt)
#pragma unroll
      for (int reg = 0; reg < 4; ++reg) {
        const int ml = wm + mt * 16 + quad * 4 + reg;
        const int nl = wn + nt * 16 + r16;
        const float v = acc[mt][nt][reg];
        if (STORE == 0) {
          ushort* Ch = (ushort*)C0 + (long)b * bC;
          ushort* Cl = (ushort*)C1 + (long)b * bC;
          const long o = (long)(m0 + ml) * ldc + n0 + nl;
          const ushort h = f2b(v);
          Ch[o] = h;
          Cl[o] = f2b(v - b2f(h));
        } else if (STORE == 1) {
          float* C = (float*)C0 + (long)b * bC + (long)tiC * TRI_ELEMS;
          C[ml * 128 + nl] = v;
        } else if (STORE == 2) {
          ushort* C = (ushort*)C0 + (long)b * bC;
          C[(long)(m0 + ml) * ldc + n0 + nl] = f2b(v);
        } else {
          float* C = (float*)C0 + (long)b * bC;
          const float* R = Res + (long)b * bR;
          const long o = (long)(m0 + ml) * ldc + n0 + nl;
          C[o] = R[o] + v;
        }
      }
}

// ---------------------------------------------------------------------------
// Causal softmax over triangular-tiled logits. One block per row (b, i).
// Writes bf16 A in tri layout, zero-filling diagonal-tile cols beyond i.
// ---------------------------------------------------------------------------
__global__ __launch_bounds__(256) void softmax_tri(
    const float* __restrict__ L, ushort* __restrict__ Aout) {
  const int row = blockIdx.x;
  const int b = row >> 11, i = row & (NN - 1);
  const int ti = i >> 7, ml = i & 127;
  const long base = (long)b * ((long)NTRI * TRI_ELEMS);
  const int trib = ti * (ti + 1) / 2;
  const int len = i + 1;
  const int tot = (ti + 1) * 128;
  const int tid = threadIdx.x;
  __shared__ float red[256];
  float vv[8];
  float m = -INFINITY;
#pragma unroll
  for (int u = 0; u < 8; ++u) {
    const int j = tid + u * 256;
    if (j < len) {
      const float v = L[base + (long)(trib + (j >> 7)) * TRI_ELEMS + ml * 128 + (j & 127)];
      vv[u] = v;
      m = fmaxf(m, v);
    }
  }
  red[tid] = m; __syncthreads();
  for (int s = 128; s; s >>= 1) { if (tid < s) red[tid] = fmaxf(red[tid], red[tid + s]); __syncthreads(); }
  m = red[0]; __syncthreads();
  float sum = 0.f;
#pragma unroll
  for (int u = 0; u < 8; ++u) {
    const int j = tid + u * 256;
    if (j < len) { const float e = __expf(vv[u] - m); vv[u] = e; sum += e; }
  }
  red[tid] = sum; __syncthreads();
  for (int s = 128; s; s >>= 1) { if (tid < s) red[tid] += red[tid + s]; __syncthreads(); }
  const float inv = 1.f / red[0];
#pragma unroll
  for (int u = 0; u < 8; ++u) {
    const int j = tid + u * 256;
    if (j < tot) {
      const ushort o = (j < len) ? f2b(vv[u] * inv) : (ushort)0;
      Aout[base + (long)(trib + (j >> 7)) * TRI_ELEMS + ml * 128 + (j & 127)] = o;
    }
  }
}

// ---------------------------------------------------------------------------
// Pipeline (all MFMA operands k-contiguous by construction):
//  0. prep: x -> x_hi, xT hi/lo; W_Q..W_O -> WT [d][k] bf16     (1 dispatch)
//  1. gemm_w: Mqk (split) + Mov (plain) in one 512-block dispatch
//  2. tT[i,d] = sum_e xT[i,e] Mqk[d,e]      split MFMA, split store, SWIZ=1
//  3. logits[i,j] = sum_d xT[i,d] tT[j,d]   split MFMA, tri tiles, SWIZ=2
//  4. A = causal softmax (bf16, tri layout, zero-padded diag tiles)
//  5. ctxT[i,e] = sum_{t<=i} A[i,t] x[e,t]  bf16 MFMA, causal K-limit, SWIZ=1
//  6. out[d,i] = x[d,i] + sum_e Mov[d,e] ctxT[i,e]   bf16 MFMA + residual
// ---------------------------------------------------------------------------
extern "C" void kernel_launch(void* const* d_in, const int* in_sizes, int n_in,
                              void* d_out, int out_size, void* d_ws, size_t ws_size,
                              hipStream_t stream) {
  const float* x = (const float*)d_in[0];
  const float* WQ = (const float*)d_in[1];
  const float* WK = (const float*)d_in[2];
  const float* WV = (const float*)d_in[3];
  const float* WO = (const float*)d_in[4];
  float* out = (float*)d_out;

  const long XE = (long)BB * DD * NN;    // 8M elements
  const long WE = (long)DD * KK;         // 1M elements
  ushort* x_hi = (ushort*)d_ws;
  ushort* xTh = x_hi + XE;
  ushort* xTl = xTh + XE;
  ushort* wqT_h = xTl + XE;
  ushort* wqT_l = wqT_h + WE;
  ushort* wkT_h = wqT_l + WE;
  ushort* wkT_l = wkT_h + WE;
  ushort* wvT_h = wkT_l + WE;
  ushort* woT_h = wvT_h + WE;
  ushort* mqk_h = woT_h + WE;
  ushort* mqk_l = mqk_h + WE;
  ushort* mov_h = mqk_l + WE;
  ushort* tTh = mov_h + WE;
  ushort* tTl = tTh + XE;
  float* logits = (float*)(tTl + XE);    // B*NTRI*TRI_ELEMS fp32 (~35.7MB)
  ushort* A_tri = tTh;                   // overlays tT hi+lo (dead after step 3)
  ushort* ctxT = (ushort*)logits;        // overlays logits (dead after softmax)
  const long TRIB = (long)NTRI * TRI_ELEMS;
  const long XB = XE / BB;

  prep<<<dim3(64, 32, 6), dim3(32, 8), 0, stream>>>(
      x, WQ, WK, WV, WO, x_hi, xTh, xTl,
      wqT_h, wqT_l, wkT_h, wkT_l, wvT_h, woT_h);

  // Mqk (split) + Mov (plain), merged 64-tile dispatch
  gemm_w<<<dim3(512), 256, 16384, stream>>>(
      wqT_h, wqT_l, wkT_h, wkT_l, wvT_h, woT_h, mqk_h, mqk_l, mov_h);

  // tT = xT * Mqk^T (split, XCD-swizzled 1-D grid)
  gemm_mfma<1, 0, 0, 1><<<dim3(512), 256, 32768, stream>>>(
      xTh, xTl, mqk_h, mqk_l, tTh, tTl, nullptr,
      DD, DD, DD, DD, XB, 0, XB, 0);

  // logits (lower tri tiles, XCD-swizzled 1-D grid)
  gemm_mfma<1, 0, 1, 2><<<dim3(BB * NTRI), 256, 32768, stream>>>(
      xTh, xTl, tTh, tTl, logits, nullptr, nullptr,
      DD, DD, DD, 0, XB, XB, TRIB, 0);

  softmax_tri<<<dim3(BB * NN), 256, 0, stream>>>(logits, A_tri);

  // ctxT = A * x^T (tri A, causal K-limit, XCD-swizzled 1-D grid)
  gemm_mfma<0, 1, 2, 1><<<dim3(512), 256, 16384, stream>>>(
      A_tri, nullptr, x_hi, nullptr, ctxT, nullptr, nullptr,
      NN, 0, NN, DD, TRIB, XB, XB, 0);

  // out = x + Mov * ctx
  gemm_mfma<0, 0, 3, 0><<<dim3(NN / 128, DD / 128, BB), 256, 16384, stream>>>(
      mov_h, nullptr, ctxT, nullptr, out, nullptr, x,
      DD, DD, DD, NN, 0, XB, XB, XB);
}

// Round 7
// 337.060 us; speedup vs baseline: 1.5179x; 1.0471x over previous
//
#include <hip/hip_runtime.h>
#include <hip/hip_bf16.h>
#include <math.h>

// Problem constants: B=4, D=1024, N=2048, K=1024, fp32 in/out.
#define BB 4
#define DD 1024
#define NN 2048
#define KK 1024
#define NT128 16            // NN/128
#define NTRI 136            // 16*17/2 lower-triangular 128x128 tiles
#define TRI_ELEMS 16384     // 128*128

typedef __attribute__((ext_vector_type(4))) float f32x4;
typedef __attribute__((ext_vector_type(8))) short bfrag;

typedef __attribute__((address_space(1))) const unsigned int gu32;
typedef __attribute__((address_space(3))) unsigned int lu32;

// async global->LDS, 16B per lane; LDS dest = base + lane*16 (wave-uniform base)
__device__ __forceinline__ void async16(const void* g, void* l) {
  __builtin_amdgcn_global_load_lds((gu32*)g, (lu32*)l, 16, 0, 0);
}

__device__ __forceinline__ ushort f2b(float f) {  // fp32 -> bf16 RNE
  union { float f; unsigned u; } c; c.f = f;
  unsigned u = c.u + 0x7fffu + ((c.u >> 16) & 1u);
  return (ushort)(u >> 16);
}
__device__ __forceinline__ float b2f(ushort h) {
  union { unsigned u; float f; } c; c.u = ((unsigned)h) << 16;
  return c.f;
}

// ---------------------------------------------------------------------------
// prep: merged input transform, grid (64, 32, 6), block (32,8).
//  z<4 : x [b=z][d][n] fp32 -> x_hi (bf16 same layout), xT hi/lo ([b][n][d])
//  z>=4: weight w = (z-4)*2 + (bx>>5): W (K x D, [k][d]) -> WT [d][k] bf16
//        (WQ, WK split hi+lo; WV, WO hi only)
// ---------------------------------------------------------------------------
__global__ __launch_bounds__(256) void prep(
    const float* __restrict__ x,
    const float* __restrict__ WQ, const float* __restrict__ WK,
    const float* __restrict__ WV, const float* __restrict__ WO,
    ushort* __restrict__ xhi, ushort* __restrict__ xTh, ushort* __restrict__ xTl,
    ushort* __restrict__ qh, ushort* __restrict__ ql,
    ushort* __restrict__ kh, ushort* __restrict__ kl_,
    ushort* __restrict__ vh, ushort* __restrict__ oh) {
  const int z = blockIdx.z;
  const int tx = threadIdx.x, ty = threadIdx.y;
  __shared__ float tile[32][33];
  if (z < 4) {
    const int b = z;
    const int n0 = blockIdx.x * 32, d0 = blockIdx.y * 32;
    const float* xb = x + (long)b * DD * NN;
    ushort* xhb = xhi + (long)b * DD * NN;
#pragma unroll
    for (int r = 0; r < 4; ++r) {
      const int dl = ty + r * 8;
      const float v = xb[(long)(d0 + dl) * NN + n0 + tx];
      tile[dl][tx] = v;
      xhb[(long)(d0 + dl) * NN + n0 + tx] = f2b(v);
    }
    __syncthreads();
#pragma unroll
    for (int r = 0; r < 4; ++r) {
      const int nl = ty + r * 8;
      const float v = tile[tx][nl];
      const ushort h = f2b(v);
      const long o = (long)b * NN * DD + (long)(n0 + nl) * DD + d0 + tx;
      xTh[o] = h;
      xTl[o] = f2b(v - b2f(h));
    }
  } else {
    const int w = (z - 4) * 2 + (blockIdx.x >> 5);
    const float* W = (w == 0) ? WQ : (w == 1) ? WK : (w == 2) ? WV : WO;
    ushort* Th = (w == 0) ? qh : (w == 1) ? kh : (w == 2) ? vh : oh;
    ushort* Tl = (w == 0) ? ql : (w == 1) ? kl_ : nullptr;
    const int k0 = (blockIdx.x & 31) * 32, d0 = blockIdx.y * 32;
#pragma unroll
    for (int r = 0; r < 4; ++r) {
      const int kl = ty + r * 8;
      tile[kl][tx] = W[(long)(k0 + kl) * DD + d0 + tx];
    }
    __syncthreads();
#pragma unroll
    for (int r = 0; r < 4; ++r) {
      const int dl = ty + r * 8;
      const float v = tile[tx][dl];              // = W[k0+tx][d0+dl]
      const ushort h = f2b(v);
      const long o = (long)(d0 + dl) * KK + k0 + tx;
      Th[o] = h;
      if (Tl) Tl[o] = f2b(v - b2f(h));
    }
  }
}

// ---------------------------------------------------------------------------
// Merged weight-product GEMM, 64x64 tiles, BK=32, 512 blocks:
//   id<256 : Mqk[m,n] = sum_k wqT[m,k] wkT[n,k]  (split 3-MFMA, split store)
//   id>=256: Mov[m,n] = sum_k woT[m,k] wvT[n,k]  (plain bf16)
// LDS rows are 32 bf16 (64B): rows alias every 2 -> XOR swizzle by (row>>1)&3.
// ---------------------------------------------------------------------------
__global__ __launch_bounds__(256) void gemm_w(
    const ushort* __restrict__ qh, const ushort* __restrict__ ql,
    const ushort* __restrict__ kh, const ushort* __restrict__ kl_,
    const ushort* __restrict__ vh, const ushort* __restrict__ oh,
    ushort* __restrict__ mqk_h, ushort* __restrict__ mqk_l,
    ushort* __restrict__ mov_h) {
  extern __shared__ ushort smem[];
  ushort* sAh = smem;            // [64][32] 4KB
  ushort* sAl = smem + 2048;
  ushort* sBh = smem + 4096;
  ushort* sBl = smem + 6144;

  const int id = blockIdx.x;
  const int half = id >> 8;                  // 0 = Mqk (split), 1 = Mov (plain)
  const int t = id & 255;
  const int m0 = (t >> 4) * 64, n0 = (t & 15) * 64;
  const ushort* A_h = half ? oh : qh;
  const ushort* B_h = half ? vh : kh;

  const int tid = threadIdx.x;
  const int lane = tid & 63, wave = tid >> 6;
  const int wm = (wave & 1) * 32, wn = (wave >> 1) * 32;
  const int r16 = lane & 15, quad = lane >> 4;
  const int kc = ((lane & 3) ^ ((lane >> 3) & 3)) * 8;   // swizzled k-chunk
  const int srow = lane >> 2;

  f32x4 acc[2][2];
#pragma unroll
  for (int i = 0; i < 2; ++i)
#pragma unroll
    for (int j = 0; j < 2; ++j) acc[i][j] = (f32x4){0.f, 0.f, 0.f, 0.f};

  for (int k0 = 0; k0 < KK; k0 += 32) {
    __syncthreads();
    {
      const int row = wave * 16 + srow;
      const long aoff = (long)(m0 + row) * KK + k0 + kc;
      const long boff = (long)(n0 + row) * KK + k0 + kc;
      async16(A_h + aoff, sAh + wave * 512);
      async16(B_h + boff, sBh + wave * 512);
      if (half == 0) {
        async16(ql + aoff, sAl + wave * 512);
        async16(kl_ + boff, sBl + wave * 512);
      }
    }
    __syncthreads();

    const int sw = (r16 >> 1) & 3;
    bfrag ah[2], bh[2], al[2], bl[2];
#pragma unroll
    for (int t2 = 0; t2 < 2; ++t2) {
      ah[t2] = *(const bfrag*)&sAh[(wm + t2 * 16 + r16) * 32 + (quad ^ sw) * 8];
      bh[t2] = *(const bfrag*)&sBh[(wn + t2 * 16 + r16) * 32 + (quad ^ sw) * 8];
      if (half == 0) {
        al[t2] = *(const bfrag*)&sAl[(wm + t2 * 16 + r16) * 32 + (quad ^ sw) * 8];
        bl[t2] = *(const bfrag*)&sBl[(wn + t2 * 16 + r16) * 32 + (quad ^ sw) * 8];
      }
    }
#pragma unroll
    for (int mt = 0; mt < 2; ++mt)
#pragma unroll
      for (int nt = 0; nt < 2; ++nt) {
        acc[mt][nt] = __builtin_amdgcn_mfma_f32_16x16x32_bf16(ah[mt], bh[nt], acc[mt][nt], 0, 0, 0);
        if (half == 0) {
          acc[mt][nt] = __builtin_amdgcn_mfma_f32_16x16x32_bf16(ah[mt], bl[nt], acc[mt][nt], 0, 0, 0);
          acc[mt][nt] = __builtin_amdgcn_mfma_f32_16x16x32_bf16(al[mt], bh[nt], acc[mt][nt], 0, 0, 0);
        }
      }
  }

#pragma unroll
  for (int mt = 0; mt < 2; ++mt)
#pragma unroll
    for (int nt = 0; nt < 2; ++nt)
#pragma unroll
      for (int reg = 0; reg < 4; ++reg) {
        const int ml = wm + mt * 16 + quad * 4 + reg;
        const int nl = wn + nt * 16 + r16;
        const float v = acc[mt][nt][reg];
        const long o = (long)(m0 + ml) * DD + n0 + nl;
        if (half == 0) {
          const ushort h = f2b(v);
          mqk_h[o] = h;
          mqk_l[o] = f2b(v - b2f(h));
        } else {
          mov_h[o] = f2b(v);
        }
      }
}

// ---------------------------------------------------------------------------
// bf16 MFMA GEMM, 128x128 block tile, 4 waves (2x2) of 64x64, BK=64,
// 16x16x32 MFMA, global_load_lds(16B) staging into swizzled LDS [128][64].
// BK=64 halves the barrier count vs BK=32; LDS = 64KB (split) -> 2 blocks/CU,
// matching the ~2 blocks/CU the 512-544 block grids supply anyway.
// Bank swizzle: rows are 128B (all 32 banks), so frag reads at a fixed chunk
// would hit the same 4 banks across all rows. Physical chunk = logical ^
// (row&7): staging lane l = (lane&7)^(lane>>3), read chunk ^= (r16&7).
// Fragment layouts (HW-verified, learn_hip m89):
//   A[m=lane&15][k=quad*8+j], B[n=lane&15][k=quad*8+j],
//   C/D: col=lane&15, row=quad*4+reg.
// SPLIT: hi+lo bf16 operands, 3 MFMAs (hh, hl, lh) ~= fp32 accuracy.
// TRIA : A staged from triangular tile layout; K limited to m0+128.
// SWIZ : XCD-locality block mapping (assumes xcd = blockIdx.x % 8):
//   1: 1-D grid 512, g=(blk&7)*64+(blk>>3); P=g>>3 -> (b=P>>4, m0=(P&15)*128),
//      n0=(g&7)*128.                                  [M=16 tiles, N=8 tiles]
//   2: 1-D grid 544 (logits tri), g=(blk&7)*68+(blk>>3); b=g/136, t=g%136.
//   3: 1-D grid 512, causal-balanced: XCD x owns mtiles {x, 15-x} (constant
//      work), idx=blk>>3: q=idx>>3 -> b=q>>1, m=(q&1)?15-x:x; n0=(idx&7)*128.
//   4: 1-D grid 512, swapped roles: P=g>>3 -> (b=P>>4, n0=(P&15)*128),
//      m0=(g&7)*128.                                  [M=8 tiles, N=16 tiles]
// STORE 0: split bf16 (C0=hi, C1=lo), row-major ldc
//       1: triangular-tile fp32
//       2: bf16 row-major
//       3: fp32 row-major with residual add from Res
// ---------------------------------------------------------------------------
template <int SPLIT, int TRIA, int STORE, int SWIZ>
__global__ __launch_bounds__(256) void gemm_mfma(
    const ushort* __restrict__ Ah, const ushort* __restrict__ Al,
    const ushort* __restrict__ Bh, const ushort* __restrict__ Bl,
    void* __restrict__ C0, void* __restrict__ C1, const float* __restrict__ Res,
    int K, int lda, int ldb, int ldc,
    long bA, long bB, long bC, long bR) {
  extern __shared__ ushort smem[];
  ushort* sAh = smem;                                    // [128][64] 16KB
  ushort* sBh = smem + (SPLIT ? 16384 : 8192);
  ushort* sAl = SPLIT ? smem + 8192 : nullptr;
  ushort* sBl = SPLIT ? smem + 24576 : nullptr;

  int b, m0, n0, tiC = 0;
  if (SWIZ == 2) {
    const int g = (blockIdx.x & 7) * 68 + (blockIdx.x >> 3);
    b = g / NTRI;
    int t = g - b * NTRI;
    int ti = 0;
    while ((ti + 1) * (ti + 2) / 2 <= t) ++ti;
    const int tj = t - ti * (ti + 1) / 2;
    m0 = ti * 128; n0 = tj * 128; tiC = t;
  } else if (SWIZ == 1) {
    const int g = (blockIdx.x & 7) * 64 + (blockIdx.x >> 3);
    const int P = g >> 3;
    b = P >> 4;
    m0 = (P & 15) * 128;
    n0 = (g & 7) * 128;
  } else if (SWIZ == 3) {
    const int xcd = blockIdx.x & 7;
    const int idx = blockIdx.x >> 3;      // [0,64)
    const int q = idx >> 3;               // [0,8)
    b = q >> 1;
    const int mt_ = (q & 1) ? (15 - xcd) : xcd;
    m0 = mt_ * 128;
    n0 = (idx & 7) * 128;
  } else {  // SWIZ == 4
    const int g = (blockIdx.x & 7) * 64 + (blockIdx.x >> 3);
    const int P = g >> 3;
    b = P >> 4;
    n0 = (P & 15) * 128;
    m0 = (g & 7) * 128;
  }
  const int kmax = TRIA ? (m0 + 128) : K;
  int triA0 = 0;
  if (TRIA) { const int ti = m0 >> 7; triA0 = ti * (ti + 1) / 2; }

  const ushort* A_h = Ah + (long)b * bA;
  const ushort* B_h = Bh + (long)b * bB;
  const ushort* A_l = SPLIT ? Al + (long)b * bA : nullptr;
  const ushort* B_l = SPLIT ? Bl + (long)b * bB : nullptr;

  const int tid = threadIdx.x;
  const int lane = tid & 63, wave = tid >> 6;
  const int wm = (wave & 1) * 64, wn = (wave >> 1) * 64;
  const int r16 = lane & 15, quad = lane >> 4;
  // staging: 8 chunks of 8 bf16 per 128B row; logical chunk for this lane
  const int kc = ((lane & 7) ^ (lane >> 3)) * 8;
  const int lrow = lane >> 3;                            // [0,8)

  f32x4 acc[4][4];
#pragma unroll
  for (int i = 0; i < 4; ++i)
#pragma unroll
    for (int j = 0; j < 4; ++j) acc[i][j] = (f32x4){0.f, 0.f, 0.f, 0.f};

  for (int k0 = 0; k0 < kmax; k0 += 64) {
    __syncthreads();
    {
#pragma unroll
      for (int c = 0; c < 4; ++c) {
        const int seg = wave * 4 + c;     // [0,16): 8-row group
        const int row = seg * 8 + lrow;
        long aoff;
        if (TRIA)
          aoff = (long)(triA0 + (k0 >> 7)) * TRI_ELEMS + (long)row * 128 + (k0 & 127) + kc;
        else
          aoff = (long)(m0 + row) * lda + k0 + kc;
        const long boff = (long)(n0 + row) * ldb + k0 + kc;
        async16(A_h + aoff, sAh + seg * 512);
        async16(B_h + boff, sBh + seg * 512);
        if (SPLIT) {
          async16(A_l + aoff, sAl + seg * 512);
          async16(B_l + boff, sBl + seg * 512);
        }
      }
    }
    __syncthreads();

    const int sw = r16 & 7;
#pragma unroll
    for (int ksub = 0; ksub < 2; ++ksub) {
      const int ch = ((ksub * 4 + quad) ^ sw) * 8;       // physical chunk
      bfrag ah[4], bh[4], al[4], bl[4];
#pragma unroll
      for (int t4 = 0; t4 < 4; ++t4) {
        ah[t4] = *(const bfrag*)&sAh[(wm + t4 * 16 + r16) * 64 + ch];
        bh[t4] = *(const bfrag*)&sBh[(wn + t4 * 16 + r16) * 64 + ch];
        if (SPLIT) {
          al[t4] = *(const bfrag*)&sAl[(wm + t4 * 16 + r16) * 64 + ch];
          bl[t4] = *(const bfrag*)&sBl[(wn + t4 * 16 + r16) * 64 + ch];
        }
      }
#pragma unroll
      for (int mt = 0; mt < 4; ++mt)
#pragma unroll
        for (int nt = 0; nt < 4; ++nt) {
          acc[mt][nt] = __builtin_amdgcn_mfma_f32_16x16x32_bf16(ah[mt], bh[nt], acc[mt][nt], 0, 0, 0);
          if (SPLIT) {
            acc[mt][nt] = __builtin_amdgcn_mfma_f32_16x16x32_bf16(ah[mt], bl[nt], acc[mt][nt], 0, 0, 0);
            acc[mt][nt] = __builtin_amdgcn_mfma_f32_16x16x32_bf16(al[mt], bh[nt], acc[mt][nt], 0, 0, 0);
          }
        }
    }
  }

  // epilogue
#pragma unroll
  for (int mt = 0; mt < 4; ++mt)
#pragma unroll
    for (int nt = 0; nt < 4; ++nt)
#pragma unroll
      for (int reg = 0; reg < 4; ++reg) {
        const int ml = wm + mt * 16 + quad * 4 + reg;
        const int nl = wn + nt * 16 + r16;
        const float v = acc[mt][nt][reg];
        if (STORE == 0) {
          ushort* Ch = (ushort*)C0 + (long)b * bC;
          ushort* Cl = (ushort*)C1 + (long)b * bC;
          const long o = (long)(m0 + ml) * ldc + n0 + nl;
          const ushort h = f2b(v);
          Ch[o] = h;
          Cl[o] = f2b(v - b2f(h));
        } else if (STORE == 1) {
          float* C = (float*)C0 + (long)b * bC + (long)tiC * TRI_ELEMS;
          C[ml * 128 + nl] = v;
        } else if (STORE == 2) {
          ushort* C = (ushort*)C0 + (long)b * bC;
          C[(long)(m0 + ml) * ldc + n0 + nl] = f2b(v);
        } else {
          float* C = (float*)C0 + (long)b * bC;
          const float* R = Res + (long)b * bR;
          const long o = (long)(m0 + ml) * ldc + n0 + nl;
          C[o] = R[o] + v;
        }
      }
}

// ---------------------------------------------------------------------------
// Causal softmax over triangular-tiled logits. One block per row (b, i).
// Writes bf16 A in tri layout, zero-filling diagonal-tile cols beyond i.
// ---------------------------------------------------------------------------
__global__ __launch_bounds__(256) void softmax_tri(
    const float* __restrict__ L, ushort* __restrict__ Aout) {
  const int row = blockIdx.x;
  const int b = row >> 11, i = row & (NN - 1);
  const int ti = i >> 7, ml = i & 127;
  const long base = (long)b * ((long)NTRI * TRI_ELEMS);
  const int trib = ti * (ti + 1) / 2;
  const int len = i + 1;
  const int tot = (ti + 1) * 128;
  const int tid = threadIdx.x;
  __shared__ float red[256];
  float vv[8];
  float m = -INFINITY;
#pragma unroll
  for (int u = 0; u < 8; ++u) {
    const int j = tid + u * 256;
    if (j < len) {
      const float v = L[base + (long)(trib + (j >> 7)) * TRI_ELEMS + ml * 128 + (j & 127)];
      vv[u] = v;
      m = fmaxf(m, v);
    }
  }
  red[tid] = m; __syncthreads();
  for (int s = 128; s; s >>= 1) { if (tid < s) red[tid] = fmaxf(red[tid], red[tid + s]); __syncthreads(); }
  m = red[0]; __syncthreads();
  float sum = 0.f;
#pragma unroll
  for (int u = 0; u < 8; ++u) {
    const int j = tid + u * 256;
    if (j < len) { const float e = __expf(vv[u] - m); vv[u] = e; sum += e; }
  }
  red[tid] = sum; __syncthreads();
  for (int s = 128; s; s >>= 1) { if (tid < s) red[tid] += red[tid + s]; __syncthreads(); }
  const float inv = 1.f / red[0];
#pragma unroll
  for (int u = 0; u < 8; ++u) {
    const int j = tid + u * 256;
    if (j < tot) {
      const ushort o = (j < len) ? f2b(vv[u] * inv) : (ushort)0;
      Aout[base + (long)(trib + (j >> 7)) * TRI_ELEMS + ml * 128 + (j & 127)] = o;
    }
  }
}

// ---------------------------------------------------------------------------
// Pipeline (all MFMA operands k-contiguous by construction):
//  0. prep: x -> x_hi, xT hi/lo; W_Q..W_O -> WT [d][k] bf16     (1 dispatch)
//  1. gemm_w: Mqk (split) + Mov (plain) in one 512-block dispatch
//  2. tT[i,d] = sum_e xT[i,e] Mqk[d,e]      split MFMA, split store, SWIZ=1
//  3. logits[i,j] = sum_d xT[i,d] tT[j,d]   split MFMA, tri tiles, SWIZ=2
//  4. A = causal softmax (bf16, tri layout, zero-padded diag tiles)
//  5. ctxT[i,e] = sum_{t<=i} A[i,t] x[e,t]  bf16 MFMA, causal K, SWIZ=3 (bal)
//  6. out[d,i] = x[d,i] + sum_e Mov[d,e] ctxT[i,e]   bf16 MFMA + res, SWIZ=4
// ---------------------------------------------------------------------------
extern "C" void kernel_launch(void* const* d_in, const int* in_sizes, int n_in,
                              void* d_out, int out_size, void* d_ws, size_t ws_size,
                              hipStream_t stream) {
  const float* x = (const float*)d_in[0];
  const float* WQ = (const float*)d_in[1];
  const float* WK = (const float*)d_in[2];
  const float* WV = (const float*)d_in[3];
  const float* WO = (const float*)d_in[4];
  float* out = (float*)d_out;

  const long XE = (long)BB * DD * NN;    // 8M elements
  const long WE = (long)DD * KK;         // 1M elements
  ushort* x_hi = (ushort*)d_ws;
  ushort* xTh = x_hi + XE;
  ushort* xTl = xTh + XE;
  ushort* wqT_h = xTl + XE;
  ushort* wqT_l = wqT_h + WE;
  ushort* wkT_h = wqT_l + WE;
  ushort* wkT_l = wkT_h + WE;
  ushort* wvT_h = wkT_l + WE;
  ushort* woT_h = wvT_h + WE;
  ushort* mqk_h = woT_h + WE;
  ushort* mqk_l = mqk_h + WE;
  ushort* mov_h = mqk_l + WE;
  ushort* tTh = mov_h + WE;
  ushort* tTl = tTh + XE;
  float* logits = (float*)(tTl + XE);    // B*NTRI*TRI_ELEMS fp32 (~35.7MB)
  ushort* A_tri = tTh;                   // overlays tT hi+lo (dead after step 3)
  ushort* ctxT = (ushort*)logits;        // overlays logits (dead after softmax)
  const long TRIB = (long)NTRI * TRI_ELEMS;
  const long XB = XE / BB;

  prep<<<dim3(64, 32, 6), dim3(32, 8), 0, stream>>>(
      x, WQ, WK, WV, WO, x_hi, xTh, xTl,
      wqT_h, wqT_l, wkT_h, wkT_l, wvT_h, woT_h);

  // Mqk (split) + Mov (plain), merged 64-tile dispatch
  gemm_w<<<dim3(512), 256, 16384, stream>>>(
      wqT_h, wqT_l, wkT_h, wkT_l, wvT_h, woT_h, mqk_h, mqk_l, mov_h);

  // tT = xT * Mqk^T (split, XCD-swizzled, BK=64, 64KB LDS)
  gemm_mfma<1, 0, 0, 1><<<dim3(512), 256, 65536, stream>>>(
      xTh, xTl, mqk_h, mqk_l, tTh, tTl, nullptr,
      DD, DD, DD, DD, XB, 0, XB, 0);

  // logits (lower tri tiles, XCD-swizzled, BK=64, 64KB LDS)
  gemm_mfma<1, 0, 1, 2><<<dim3(BB * NTRI), 256, 65536, stream>>>(
      xTh, xTl, tTh, tTl, logits, nullptr, nullptr,
      DD, DD, DD, 0, XB, XB, TRIB, 0);

  softmax_tri<<<dim3(BB * NN), 256, 0, stream>>>(logits, A_tri);

  // ctxT = A * x^T (tri A, causal K-limit, balanced XCD swizzle)
  gemm_mfma<0, 1, 2, 3><<<dim3(512), 256, 32768, stream>>>(
      A_tri, nullptr, x_hi, nullptr, ctxT, nullptr, nullptr,
      NN, 0, NN, DD, TRIB, XB, XB, 0);

  // out = x + Mov * ctx (SWIZ=4: M=8 d-tiles, N=16 i-tiles)
  gemm_mfma<0, 0, 3, 4><<<dim3(512), 256, 32768, stream>>>(
      mov_h, nullptr, ctxT, nullptr, out, nullptr, x,
      DD, DD, DD, NN, 0, XB, XB, XB);
}